// Round 5
// baseline (1094.401 us; speedup 1.0000x reference)
//
#include <hip/hip_runtime.h>
#include <math.h>

#define NB 4
#define NPI 12000
#define NM 32
#define NPTS (NB*NPI*NM)      // 1536000
#define NPIL (NB*NPI)         // 48000

// k_moments config
#define K1_BLOCKS 1500
#define K1_STRIDE (K1_BLOCKS*256)   // 384000
#define K1_ITERS 4                  // NPTS / K1_STRIDE
#define NMOM 55                     // 9 Sf + 45 Sff + 1 valid-count

// heavy-kernel config: wave-per-pillar, no intra-loop barriers
#define SB 1024               // blocks for k_stats2 / k_out (4096 waves)
#define NWAVES (SB*4)
#define LDH 68                // padded h1 row stride (floats)

// ---------------------------------------------------------------- helpers

__device__ __forceinline__ void make_f(float4 v, int4 cc, int np, int m, float zc, float f[9]) {
  const float cx = ((float)cc.w + 0.5f) * 0.16f + 0.0f;
  const float cy = ((float)cc.z + 0.5f) * 0.16f - 39.68f;
  f[0] = v.x; f[1] = v.y; f[2] = v.z; f[3] = v.w;
  f[4] = v.x - cx; f[5] = v.y - cy; f[6] = cx; f[7] = cy; f[8] = zc;
  const float msk = (m < np) ? 1.0f : 0.0f;
#pragma unroll
  for (int i = 0; i < 9; ++i) f[i] *= msk;
}

// ------------------------------------------------- K1: f-moments + valid count

__global__ __launch_bounds__(256) void k_moments(
    const float4* __restrict__ vox, const int4* __restrict__ coords,
    const int* __restrict__ npnts, float* __restrict__ P1) {
  const int t = blockIdx.x * 256 + threadIdx.x;
  float acc[NMOM];
#pragma unroll
  for (int v = 0; v < NMOM; ++v) acc[v] = 0.0f;

#pragma unroll
  for (int j = 0; j < K1_ITERS; ++j) {
    const int pt = t + j * K1_STRIDE;
    const int pil = pt >> 5;
    const int m = pt & 31;
    const float4 v = vox[pt];
    const int4 cc = coords[pil];
    const int np = npnts[pil];
    float z = v.z;
#pragma unroll
    for (int s = 1; s < 32; s <<= 1) z += __shfl_xor(z, s, 32);
    const float zc = z * (1.0f / 32.0f);
    float f[9];
    make_f(v, cc, np, m, zc, f);
    int vi = 0;
#pragma unroll
    for (int i = 0; i < 9; ++i) acc[vi++] += f[i];
#pragma unroll
    for (int i = 0; i < 9; ++i)
#pragma unroll
      for (int jj = i; jj < 9; ++jj) acc[vi++] += f[i] * f[jj];
    acc[54] += (m < np) ? 1.0f : 0.0f;
  }

#pragma unroll
  for (int v = 0; v < NMOM; ++v) {
    float x = acc[v];
#pragma unroll
    for (int s = 1; s < 64; s <<= 1) x += __shfl_xor(x, s, 64);
    acc[v] = x;
  }
  __shared__ float red[4][NMOM];
  const int wave = threadIdx.x >> 6, lane = threadIdx.x & 63;
  if (lane == 0) {
#pragma unroll
    for (int v = 0; v < NMOM; ++v) red[wave][v] = acc[v];
  }
  __syncthreads();
  if (threadIdx.x < NMOM) {
    float s = red[0][threadIdx.x] + red[1][threadIdx.x] + red[2][threadIdx.x] + red[3][threadIdx.x];
    P1[threadIdx.x * K1_BLOCKS + blockIdx.x] = s;
  }
}

// ------------------------------------------------- generic row reduce (f32 -> f64)

__global__ __launch_bounds__(256) void k_rowreduce(
    const float* __restrict__ src, double* __restrict__ dst, int ncols) {
  const int row = blockIdx.x;
  const float* p = src + row * ncols;
  double sd = 0.0;
  for (int i = threadIdx.x; i < ncols; i += 256) sd += (double)p[i];
#pragma unroll
  for (int s = 1; s < 64; s <<= 1) sd += __shfl_xor(sd, s, 64);
  __shared__ double rd[4];
  const int wave = threadIdx.x >> 6, lane = threadIdx.x & 63;
  if (lane == 0) rd[wave] = sd;
  __syncthreads();
  if (threadIdx.x == 0) dst[row] = rd[0] + rd[1] + rd[2] + rd[3];
}

// ------------------------------------------------- finalize layer-1 BN params

__global__ void k_fin1(const double* __restrict__ T1, const float* __restrict__ W1,
                       const float* __restrict__ g1, const float* __restrict__ b1,
                       float* __restrict__ params) {
  const int c = threadIdx.x;  // 64
  double w[9];
#pragma unroll
  for (int i = 0; i < 9; ++i) w[i] = (double)W1[i * 64 + c];
  double mean = 0.0;
#pragma unroll
  for (int i = 0; i < 9; ++i) mean += w[i] * T1[i];
  mean /= (double)NPTS;
  double e2 = 0.0;
  int v = 9;
#pragma unroll
  for (int i = 0; i < 9; ++i)
#pragma unroll
    for (int j = i; j < 9; ++j) {
      const double t = T1[v++] * w[i] * w[j];
      e2 += (i == j) ? t : 2.0 * t;
    }
  e2 /= (double)NPTS;
  const double var = e2 - mean * mean;
  const double a = (double)g1[c] / sqrt(var + 0.001);
  params[c] = (float)a;
  params[64 + c] = (float)((double)b1[c] - mean * a);
}

// ------------------------------------------------- K3: layer-2 stats
// Wave-per-pillar: phase A fills this wave's private h1 region (no barrier
// needed -- only the producing wave reads it; within-wave ds ordering via
// lgkmcnt). Phase B: lane=channel, loop pp < np of own pillar.

__global__ __launch_bounds__(256, 2) void k_stats2(
    const float4* __restrict__ vox, const int4* __restrict__ coords,
    const int* __restrict__ npnts, const float* __restrict__ W1,
    const float* __restrict__ W2, const float* __restrict__ params,
    float* __restrict__ P2) {
  __shared__ __align__(16) float W1t[9 * 64];
  __shared__ __align__(16) float a1s[64], b1s[64];
  __shared__ __align__(16) float h1s[4 * 32 * LDH];   // 34816 B, per-wave regions
  __shared__ float redS[4][64], redQ[4][64];

  const int t = threadIdx.x;
  for (int i = t; i < 576; i += 256) W1t[i] = W1[i];
  if (t < 64) { a1s[t] = params[t]; b1s[t] = params[64 + t]; }

  const int lane = t & 63, wv = t >> 6;
  const int m = lane & 31, half = lane >> 5;
  float w2[64];
#pragma unroll
  for (int k = 0; k < 64; ++k) w2[k] = W2[k * 64 + lane];
  __syncthreads();   // staging of W1t/a1s/b1s only

  float* const wrow = &h1s[wv * 32 * LDH];
  float psum = 0.0f, psq = 0.0f;

  for (int pil = blockIdx.x * 4 + wv; pil < NPIL; pil += NWAVES) {
    // ---- phase A: h1 for this pillar's 32 points (2 lanes/point)
    const float4 v = vox[pil * 32 + m];
    const int4 cc = coords[pil];
    const int np = npnts[pil];
    float z = v.z;
#pragma unroll
    for (int s = 1; s < 64; s <<= 1) z += __shfl_xor(z, s, 64);  // 32 pts x2
    const float zc = z * (1.0f / 64.0f);
    float f[9];
    make_f(v, cc, np, m, zc, f);
#pragma unroll
    for (int j = 0; j < 8; ++j) {
      const int c0 = half * 32 + 4 * j;
      float y0 = 0, y1 = 0, y2 = 0, y3 = 0;
#pragma unroll
      for (int i = 0; i < 9; ++i) {
        const float4 w = *(const float4*)&W1t[i * 64 + c0];
        y0 = fmaf(f[i], w.x, y0);
        y1 = fmaf(f[i], w.y, y1);
        y2 = fmaf(f[i], w.z, y2);
        y3 = fmaf(f[i], w.w, y3);
      }
      const float4 a = *(const float4*)&a1s[c0];
      const float4 b = *(const float4*)&b1s[c0];
      float4 h;
      h.x = fmaxf(fmaf(y0, a.x, b.x), 0.0f);
      h.y = fmaxf(fmaf(y1, a.y, b.y), 0.0f);
      h.z = fmaxf(fmaf(y2, a.z, b.z), 0.0f);
      h.w = fmaxf(fmaf(y3, a.w, b.w), 0.0f);
      *(float4*)&wrow[m * LDH + c0] = h;
    }
    // ---- phase B: valid points only (np is wave-uniform)
#pragma unroll 2
    for (int pp = 0; pp < np; ++pp) {
      const float4* hr = (const float4*)&wrow[pp * LDH];
      float y0 = 0, y1 = 0, y2 = 0, y3 = 0;
#pragma unroll
      for (int a4 = 0; a4 < 16; ++a4) {
        const float4 hv = hr[a4];   // broadcast read
        y0 = fmaf(hv.x, w2[4 * a4 + 0], y0);
        y1 = fmaf(hv.y, w2[4 * a4 + 1], y1);
        y2 = fmaf(hv.z, w2[4 * a4 + 2], y2);
        y3 = fmaf(hv.w, w2[4 * a4 + 3], y3);
      }
      const float y = (y0 + y1) + (y2 + y3);
      psum += y;
      psq = fmaf(y, y, psq);
    }
  }

  redS[wv][lane] = psum;
  redQ[wv][lane] = psq;
  __syncthreads();
  if (t < 64) {
    const float s = redS[0][t] + redS[1][t] + redS[2][t] + redS[3][t];
    const float q = redQ[0][t] + redQ[1][t] + redQ[2][t] + redQ[3][t];
    P2[t * SB + blockIdx.x] = s;
    P2[(64 + t) * SB + blockIdx.x] = q;
  }
}

// ------------------------------------------------- finalize layer-2 BN params
// Adds masked-point contributions in closed form; precomputes h2_0 for k_out.

__global__ void k_fin2(const double* __restrict__ T2, const float* __restrict__ g2,
                       const float* __restrict__ b2, const float* __restrict__ W2,
                       const double* __restrict__ T1, float* __restrict__ params) {
  const int c = threadIdx.x;  // 64
  const double nmask = (double)NPTS - T1[54];
  double y20 = 0.0;
  for (int k = 0; k < 64; ++k) {
    const float h0 = fmaxf(params[64 + k], 0.0f);   // h1_0[k] = relu(b1adj[k])
    y20 += (double)h0 * (double)W2[k * 64 + c];
  }
  const double sum = T2[c] + nmask * y20;
  const double sq  = T2[64 + c] + nmask * y20 * y20;
  const double mean = sum / (double)NPTS;
  const double var = sq / (double)NPTS - mean * mean;
  const double a = (double)g2[c] / sqrt(var + 0.001);
  const double badj = (double)b2[c] - mean * a;
  params[128 + c] = (float)a;
  params[192 + c] = (float)badj;
  params[256 + c] = (float)fmax(a * y20 + badj, 0.0);   // h2_0[c] (relu)
}

// ------------------------------------------------- K5: output pass (wave-per-pillar)

__global__ __launch_bounds__(256, 2) void k_out(
    const float4* __restrict__ vox, const int4* __restrict__ coords,
    const int* __restrict__ npnts, const float* __restrict__ W1,
    const float* __restrict__ W2, const float* __restrict__ params,
    float* __restrict__ out) {
  __shared__ __align__(16) float W1t[9 * 64];
  __shared__ __align__(16) float a1s[64], b1s[64];
  __shared__ __align__(16) float h1s[4 * 32 * LDH];

  const int t = threadIdx.x;
  for (int i = t; i < 576; i += 256) W1t[i] = W1[i];
  if (t < 64) { a1s[t] = params[t]; b1s[t] = params[64 + t]; }

  const int lane = t & 63, wv = t >> 6;
  const int m = lane & 31, half = lane >> 5;
  float w2[64];
#pragma unroll
  for (int k = 0; k < 64; ++k) w2[k] = W2[k * 64 + lane];
  const float a2 = params[128 + lane];
  const float b2 = params[192 + lane];
  const float h20 = params[256 + lane];
  __syncthreads();

  float* const wrow = &h1s[wv * 32 * LDH];

  for (int pil = blockIdx.x * 4 + wv; pil < NPIL; pil += NWAVES) {
    const float4 v = vox[pil * 32 + m];
    const int4 cc = coords[pil];
    const int np = npnts[pil];
    float z = v.z;
#pragma unroll
    for (int s = 1; s < 64; s <<= 1) z += __shfl_xor(z, s, 64);
    const float zc = z * (1.0f / 64.0f);
    float f[9];
    make_f(v, cc, np, m, zc, f);
#pragma unroll
    for (int j = 0; j < 8; ++j) {
      const int c0 = half * 32 + 4 * j;
      float y0 = 0, y1 = 0, y2 = 0, y3 = 0;
#pragma unroll
      for (int i = 0; i < 9; ++i) {
        const float4 w = *(const float4*)&W1t[i * 64 + c0];
        y0 = fmaf(f[i], w.x, y0);
        y1 = fmaf(f[i], w.y, y1);
        y2 = fmaf(f[i], w.z, y2);
        y3 = fmaf(f[i], w.w, y3);
      }
      const float4 a = *(const float4*)&a1s[c0];
      const float4 b = *(const float4*)&b1s[c0];
      float4 h;
      h.x = fmaxf(fmaf(y0, a.x, b.x), 0.0f);
      h.y = fmaxf(fmaf(y1, a.y, b.y), 0.0f);
      h.z = fmaxf(fmaf(y2, a.z, b.z), 0.0f);
      h.w = fmaxf(fmaf(y3, a.w, b.w), 0.0f);
      *(float4*)&wrow[m * LDH + c0] = h;
    }
    // phase B: valid points only; masked points all give h2_0 (folded below)
    float mx = 0.0f;   // h2 = relu >= 0
#pragma unroll 2
    for (int pp = 0; pp < np; ++pp) {
      const float4* hr = (const float4*)&wrow[pp * LDH];
      float y0 = 0, y1 = 0, y2 = 0, y3 = 0;
#pragma unroll
      for (int a4 = 0; a4 < 16; ++a4) {
        const float4 hv = hr[a4];
        y0 = fmaf(hv.x, w2[4 * a4 + 0], y0);
        y1 = fmaf(hv.y, w2[4 * a4 + 1], y1);
        y2 = fmaf(hv.z, w2[4 * a4 + 2], y2);
        y3 = fmaf(hv.w, w2[4 * a4 + 3], y3);
      }
      const float y = (y0 + y1) + (y2 + y3);
      mx = fmaxf(mx, fmaxf(fmaf(y, a2, b2), 0.0f));
    }
    if (np < 32) mx = fmaxf(mx, h20);
    out[pil * 64 + lane] = mx;
  }
}

// ---------------------------------------------------------------- launch

extern "C" void kernel_launch(void* const* d_in, const int* in_sizes, int n_in,
                              void* d_out, int out_size, void* d_ws, size_t ws_size,
                              hipStream_t stream) {
  const float4* vox = (const float4*)d_in[0];
  const int4* coords = (const int4*)d_in[1];
  const int* npnts = (const int*)d_in[2];
  const float* W1 = (const float*)d_in[3];
  const float* g1 = (const float*)d_in[4];
  const float* b1 = (const float*)d_in[5];
  const float* W2 = (const float*)d_in[6];
  const float* g2 = (const float*)d_in[7];
  const float* b2 = (const float*)d_in[8];
  float* out = (float*)d_out;

  char* w = (char*)d_ws;
  double* T1 = (double*)w;                                   // 55 doubles
  double* T2 = (double*)(w + 512);                           // 128 doubles
  float* P1 = (float*)(w + 1536);                            // 55*1500 f32
  float* P2 = (float*)(w + 1536 + NMOM * K1_BLOCKS * 4);     // 128*SB f32
  float* params = (float*)(w + 1536 + NMOM * K1_BLOCKS * 4 + 128 * SB * 4);  // 320 f32

  k_moments<<<K1_BLOCKS, 256, 0, stream>>>(vox, coords, npnts, P1);
  k_rowreduce<<<NMOM, 256, 0, stream>>>(P1, T1, K1_BLOCKS);
  k_fin1<<<1, 64, 0, stream>>>(T1, W1, g1, b1, params);
  k_stats2<<<SB, 256, 0, stream>>>(vox, coords, npnts, W1, W2, params, P2);
  k_rowreduce<<<128, 256, 0, stream>>>(P2, T2, SB);
  k_fin2<<<1, 64, 0, stream>>>(T2, g2, b2, W2, T1, params);
  k_out<<<SB, 256, 0, stream>>>(vox, coords, npnts, W1, W2, params, out);
}

// Round 6
// 567.296 us; speedup vs baseline: 1.9292x; 1.9292x over previous
//
#include <hip/hip_runtime.h>
#include <math.h>

#define NB 4
#define NPI 12000
#define NM 32
#define NPTS (NB*NPI*NM)      // 1536000
#define NPIL (NB*NPI)         // 48000

// k_moments config
#define K1_BLOCKS 1500
#define K1_STRIDE (K1_BLOCKS*256)   // 384000
#define K1_ITERS 4                  // NPTS / K1_STRIDE
#define NMOM 55                     // 9 Sf + 45 Sff + 1 valid-count

// heavy-kernel config: 128 points (4 sorted pillars) per batch
#define CHUNK 128
#define NBATCH (NPTS/CHUNK)   // 12000
#define SB 1024               // grid for k_stats2 / k_out
#define LDH 68                // padded h1 row stride (floats)

// sort config
#define SLICE 188             // 256*188 = 48128 >= NPIL

// ---------------------------------------------------------------- helpers

__device__ __forceinline__ void make_f(float4 v, int4 cc, int np, int m, float zc, float f[9]) {
  const float cx = ((float)cc.w + 0.5f) * 0.16f + 0.0f;
  const float cy = ((float)cc.z + 0.5f) * 0.16f - 39.68f;
  f[0] = v.x; f[1] = v.y; f[2] = v.z; f[3] = v.w;
  f[4] = v.x - cx; f[5] = v.y - cy; f[6] = cx; f[7] = cy; f[8] = zc;
  const float msk = (m < np) ? 1.0f : 0.0f;
#pragma unroll
  for (int i = 0; i < 9; ++i) f[i] *= msk;
}

// ------------------------------------------------- K0: stable counting sort of
// pillars by np (33 bins). Single block, deterministic (pure integer ops,
// fixed order). perm[pos] = pillar id, np ascending, stable.

__global__ __launch_bounds__(256) void k_sort(
    const int* __restrict__ npnts, int* __restrict__ perm) {
  __shared__ int C[33][256];   // per-bin, per-thread counts -> running starts
  __shared__ int T[33], O[33];
  const int t = threadIdx.x;
#pragma unroll
  for (int b = 0; b < 33; ++b) C[b][t] = 0;
  __syncthreads();
  const int i0 = t * SLICE;
  const int i1 = (i0 + SLICE < NPIL) ? i0 + SLICE : NPIL;
  for (int i = i0; i < i1; ++i) C[npnts[i]][t]++;   // column t private
  __syncthreads();
  if (t < 33) { int s = 0; for (int j = 0; j < 256; ++j) s += C[t][j]; T[t] = s; }
  __syncthreads();
  if (t == 0) { int r = 0; for (int b = 0; b < 33; ++b) { O[b] = r; r += T[b]; } }
  __syncthreads();
  if (t < 33) {
    int r = O[t];
    for (int j = 0; j < 256; ++j) { const int c = C[t][j]; C[t][j] = r; r += c; }
  }
  __syncthreads();
  for (int i = i0; i < i1; ++i) {
    const int b = npnts[i];
    const int p = C[b][t];
    C[b][t] = p + 1;
    perm[p] = i;
  }
}

// ------------------------------------------------- K1: f-moments + valid count

__global__ __launch_bounds__(256) void k_moments(
    const float4* __restrict__ vox, const int4* __restrict__ coords,
    const int* __restrict__ npnts, float* __restrict__ P1) {
  const int t = blockIdx.x * 256 + threadIdx.x;
  float acc[NMOM];
#pragma unroll
  for (int v = 0; v < NMOM; ++v) acc[v] = 0.0f;

#pragma unroll
  for (int j = 0; j < K1_ITERS; ++j) {
    const int pt = t + j * K1_STRIDE;
    const int pil = pt >> 5;
    const int m = pt & 31;
    const float4 v = vox[pt];
    const int4 cc = coords[pil];
    const int np = npnts[pil];
    float z = v.z;
#pragma unroll
    for (int s = 1; s < 32; s <<= 1) z += __shfl_xor(z, s, 32);
    const float zc = z * (1.0f / 32.0f);
    float f[9];
    make_f(v, cc, np, m, zc, f);
    int vi = 0;
#pragma unroll
    for (int i = 0; i < 9; ++i) acc[vi++] += f[i];
#pragma unroll
    for (int i = 0; i < 9; ++i)
#pragma unroll
      for (int jj = i; jj < 9; ++jj) acc[vi++] += f[i] * f[jj];
    acc[54] += (m < np) ? 1.0f : 0.0f;
  }

#pragma unroll
  for (int v = 0; v < NMOM; ++v) {
    float x = acc[v];
#pragma unroll
    for (int s = 1; s < 64; s <<= 1) x += __shfl_xor(x, s, 64);
    acc[v] = x;
  }
  __shared__ float red[4][NMOM];
  const int wave = threadIdx.x >> 6, lane = threadIdx.x & 63;
  if (lane == 0) {
#pragma unroll
    for (int v = 0; v < NMOM; ++v) red[wave][v] = acc[v];
  }
  __syncthreads();
  if (threadIdx.x < NMOM) {
    float s = red[0][threadIdx.x] + red[1][threadIdx.x] + red[2][threadIdx.x] + red[3][threadIdx.x];
    P1[threadIdx.x * K1_BLOCKS + blockIdx.x] = s;
  }
}

// ------------------------------------------------- generic row reduce (f32 -> f64)

__global__ __launch_bounds__(256) void k_rowreduce(
    const float* __restrict__ src, double* __restrict__ dst, int ncols) {
  const int row = blockIdx.x;
  const float* p = src + row * ncols;
  double sd = 0.0;
  for (int i = threadIdx.x; i < ncols; i += 256) sd += (double)p[i];
#pragma unroll
  for (int s = 1; s < 64; s <<= 1) sd += __shfl_xor(sd, s, 64);
  __shared__ double rd[4];
  const int wave = threadIdx.x >> 6, lane = threadIdx.x & 63;
  if (lane == 0) rd[wave] = sd;
  __syncthreads();
  if (threadIdx.x == 0) dst[row] = rd[0] + rd[1] + rd[2] + rd[3];
}

// ------------------------------------------------- finalize layer-1 BN params

__global__ void k_fin1(const double* __restrict__ T1, const float* __restrict__ W1,
                       const float* __restrict__ g1, const float* __restrict__ b1,
                       float* __restrict__ params) {
  const int c = threadIdx.x;  // 64
  double w[9];
#pragma unroll
  for (int i = 0; i < 9; ++i) w[i] = (double)W1[i * 64 + c];
  double mean = 0.0;
#pragma unroll
  for (int i = 0; i < 9; ++i) mean += w[i] * T1[i];
  mean /= (double)NPTS;
  double e2 = 0.0;
  int v = 9;
#pragma unroll
  for (int i = 0; i < 9; ++i)
#pragma unroll
    for (int j = i; j < 9; ++j) {
      const double t = T1[v++] * w[i] * w[j];
      e2 += (i == j) ? t : 2.0 * t;
    }
  e2 /= (double)NPTS;
  const double var = e2 - mean * mean;
  const double a = (double)g1[c] / sqrt(var + 0.001);
  params[c] = (float)a;
  params[64 + c] = (float)((double)b1[c] - mean * a);
}

// ------------------------------------------------- K3: layer-2 stats
// Round-4 structure (barrier between phases = also a register-pressure fence;
// round 5's barrier-free variant spilled). Pillars taken via perm[] so each
// chunk's 4 pillars have ~equal np -> barrier max ~= mean.

__global__ __launch_bounds__(256, 4) void k_stats2(
    const float4* __restrict__ vox, const int4* __restrict__ coords,
    const int* __restrict__ npnts, const float* __restrict__ W1,
    const float* __restrict__ W2, const float* __restrict__ params,
    const int* __restrict__ perm, float* __restrict__ P2) {
  __shared__ __align__(16) float W1t[9 * 64];
  __shared__ __align__(16) float a1s[64], b1s[64];
  __shared__ __align__(16) float h1s[CHUNK * LDH];
  __shared__ float redS[4][64], redQ[4][64];

  const int t = threadIdx.x;
  for (int i = t; i < 576; i += 256) W1t[i] = W1[i];
  if (t < 64) { a1s[t] = params[t]; b1s[t] = params[64 + t]; }

  const int c = t & 63;
  float w2[64];
#pragma unroll
  for (int k = 0; k < 64; ++k) w2[k] = W2[k * 64 + c];
  __syncthreads();

  const int p_loc = t >> 1;
  const int ch_half = (t & 1) * 32;
  const int g = t >> 6;
  float psum = 0.0f, psq = 0.0f;

  for (int bb = blockIdx.x; bb < NBATCH; bb += SB) {
    // ---- phase A: h1 for 128 points (4 permuted pillars)
    const int pid = perm[bb * 4 + (p_loc >> 5)];
    const int m = p_loc & 31;
    const float4 v = vox[pid * 32 + m];
    const int4 cc = coords[pid];
    const int np = npnts[pid];
    float z = v.z;
#pragma unroll
    for (int s = 1; s < 64; s <<= 1) z += __shfl_xor(z, s, 64);  // 32 pts x2 lanes
    const float zc = z * (1.0f / 64.0f);
    float f[9];
    make_f(v, cc, np, m, zc, f);
    float* row = &h1s[p_loc * LDH];
#pragma unroll
    for (int j = 0; j < 8; ++j) {
      const int c0 = ch_half + 4 * j;
      float y0 = 0, y1 = 0, y2 = 0, y3 = 0;
#pragma unroll
      for (int i = 0; i < 9; ++i) {
        const float4 w = *(const float4*)&W1t[i * 64 + c0];
        y0 = fmaf(f[i], w.x, y0);
        y1 = fmaf(f[i], w.y, y1);
        y2 = fmaf(f[i], w.z, y2);
        y3 = fmaf(f[i], w.w, y3);
      }
      const float4 a = *(const float4*)&a1s[c0];
      const float4 b = *(const float4*)&b1s[c0];
      float4 h;
      h.x = fmaxf(fmaf(y0, a.x, b.x), 0.0f);
      h.y = fmaxf(fmaf(y1, a.y, b.y), 0.0f);
      h.z = fmaxf(fmaf(y2, a.z, b.z), 0.0f);
      h.w = fmaxf(fmaf(y3, a.w, b.w), 0.0f);
      *(float4*)&row[c0] = h;
    }
    __syncthreads();
    // ---- phase B: valid points only (np_g wave-uniform; sorted -> max ~= mean)
    const int np_g = npnts[perm[bb * 4 + g]];
#pragma unroll 2
    for (int pp = 0; pp < np_g; ++pp) {
      const float4* hr = (const float4*)&h1s[(g * 32 + pp) * LDH];
      float y0 = 0, y1 = 0, y2 = 0, y3 = 0;
#pragma unroll
      for (int a4 = 0; a4 < 16; ++a4) {
        const float4 hv = hr[a4];   // broadcast read
        y0 = fmaf(hv.x, w2[4 * a4 + 0], y0);
        y1 = fmaf(hv.y, w2[4 * a4 + 1], y1);
        y2 = fmaf(hv.z, w2[4 * a4 + 2], y2);
        y3 = fmaf(hv.w, w2[4 * a4 + 3], y3);
      }
      const float y = (y0 + y1) + (y2 + y3);
      psum += y;
      psq = fmaf(y, y, psq);
    }
    __syncthreads();
  }

  const int wave = t >> 6;
  redS[wave][c] = psum;
  redQ[wave][c] = psq;
  __syncthreads();
  if (t < 64) {
    const float s = redS[0][t] + redS[1][t] + redS[2][t] + redS[3][t];
    const float q = redQ[0][t] + redQ[1][t] + redQ[2][t] + redQ[3][t];
    P2[t * SB + blockIdx.x] = s;
    P2[(64 + t) * SB + blockIdx.x] = q;
  }
}

// ------------------------------------------------- finalize layer-2 BN params

__global__ void k_fin2(const double* __restrict__ T2, const float* __restrict__ g2,
                       const float* __restrict__ b2, const float* __restrict__ W2,
                       const double* __restrict__ T1, float* __restrict__ params) {
  const int c = threadIdx.x;  // 64
  const double nmask = (double)NPTS - T1[54];
  double y20 = 0.0;
  for (int k = 0; k < 64; ++k) {
    const float h0 = fmaxf(params[64 + k], 0.0f);   // h1_0[k] = relu(b1adj[k])
    y20 += (double)h0 * (double)W2[k * 64 + c];
  }
  const double sum = T2[c] + nmask * y20;
  const double sq  = T2[64 + c] + nmask * y20 * y20;
  const double mean = sum / (double)NPTS;
  const double var = sq / (double)NPTS - mean * mean;
  const double a = (double)g2[c] / sqrt(var + 0.001);
  const double badj = (double)b2[c] - mean * a;
  params[128 + c] = (float)a;
  params[192 + c] = (float)badj;
  params[256 + c] = (float)fmax(a * y20 + badj, 0.0);   // h2_0[c] (relu)
}

// ------------------------------------------------- K5: output pass (sorted pillars)

__global__ __launch_bounds__(256, 2) void k_out(
    const float4* __restrict__ vox, const int4* __restrict__ coords,
    const int* __restrict__ npnts, const float* __restrict__ W1,
    const float* __restrict__ W2, const float* __restrict__ params,
    const int* __restrict__ perm, float* __restrict__ out) {
  __shared__ __align__(16) float W1t[9 * 64];
  __shared__ __align__(16) float a1s[64], b1s[64];
  __shared__ __align__(16) float h1s[CHUNK * LDH];

  const int t = threadIdx.x;
  for (int i = t; i < 576; i += 256) W1t[i] = W1[i];
  if (t < 64) { a1s[t] = params[t]; b1s[t] = params[64 + t]; }

  const int c = t & 63;
  float w2[64];
#pragma unroll
  for (int k = 0; k < 64; ++k) w2[k] = W2[k * 64 + c];
  const float a2 = params[128 + c];
  const float b2 = params[192 + c];
  const float h20 = params[256 + c];
  __syncthreads();

  const int p_loc = t >> 1;
  const int ch_half = (t & 1) * 32;
  const int g = t >> 6;

  for (int bb = blockIdx.x; bb < NBATCH; bb += SB) {
    const int pid = perm[bb * 4 + (p_loc >> 5)];
    const int m = p_loc & 31;
    const float4 v = vox[pid * 32 + m];
    const int4 cc = coords[pid];
    const int np = npnts[pid];
    float z = v.z;
#pragma unroll
    for (int s = 1; s < 64; s <<= 1) z += __shfl_xor(z, s, 64);
    const float zc = z * (1.0f / 64.0f);
    float f[9];
    make_f(v, cc, np, m, zc, f);
    float* row = &h1s[p_loc * LDH];
#pragma unroll
    for (int j = 0; j < 8; ++j) {
      const int c0 = ch_half + 4 * j;
      float y0 = 0, y1 = 0, y2 = 0, y3 = 0;
#pragma unroll
      for (int i = 0; i < 9; ++i) {
        const float4 w = *(const float4*)&W1t[i * 64 + c0];
        y0 = fmaf(f[i], w.x, y0);
        y1 = fmaf(f[i], w.y, y1);
        y2 = fmaf(f[i], w.z, y2);
        y3 = fmaf(f[i], w.w, y3);
      }
      const float4 a = *(const float4*)&a1s[c0];
      const float4 b = *(const float4*)&b1s[c0];
      float4 h;
      h.x = fmaxf(fmaf(y0, a.x, b.x), 0.0f);
      h.y = fmaxf(fmaf(y1, a.y, b.y), 0.0f);
      h.z = fmaxf(fmaf(y2, a.z, b.z), 0.0f);
      h.w = fmaxf(fmaf(y3, a.w, b.w), 0.0f);
      *(float4*)&row[c0] = h;
    }
    __syncthreads();
    // phase B: valid points only; masked points all give h2_0 (folded below)
    const int pidB = perm[bb * 4 + g];
    const int np_g = npnts[pidB];
    float mx = 0.0f;   // h2 = relu >= 0
#pragma unroll 2
    for (int pp = 0; pp < np_g; ++pp) {
      const float4* hr = (const float4*)&h1s[(g * 32 + pp) * LDH];
      float y0 = 0, y1 = 0, y2 = 0, y3 = 0;
#pragma unroll
      for (int a4 = 0; a4 < 16; ++a4) {
        const float4 hv = hr[a4];
        y0 = fmaf(hv.x, w2[4 * a4 + 0], y0);
        y1 = fmaf(hv.y, w2[4 * a4 + 1], y1);
        y2 = fmaf(hv.z, w2[4 * a4 + 2], y2);
        y3 = fmaf(hv.w, w2[4 * a4 + 3], y3);
      }
      const float y = (y0 + y1) + (y2 + y3);
      mx = fmaxf(mx, fmaxf(fmaf(y, a2, b2), 0.0f));
    }
    if (np_g < 32) mx = fmaxf(mx, h20);
    out[pidB * 64 + c] = mx;
    __syncthreads();
  }
}

// ---------------------------------------------------------------- launch

extern "C" void kernel_launch(void* const* d_in, const int* in_sizes, int n_in,
                              void* d_out, int out_size, void* d_ws, size_t ws_size,
                              hipStream_t stream) {
  const float4* vox = (const float4*)d_in[0];
  const int4* coords = (const int4*)d_in[1];
  const int* npnts = (const int*)d_in[2];
  const float* W1 = (const float*)d_in[3];
  const float* g1 = (const float*)d_in[4];
  const float* b1 = (const float*)d_in[5];
  const float* W2 = (const float*)d_in[6];
  const float* g2 = (const float*)d_in[7];
  const float* b2 = (const float*)d_in[8];
  float* out = (float*)d_out;

  char* w = (char*)d_ws;
  double* T1 = (double*)w;                                   // 55 doubles
  double* T2 = (double*)(w + 512);                           // 128 doubles
  float* P1 = (float*)(w + 1536);                            // 55*1500 f32
  float* P2 = (float*)(w + 1536 + NMOM * K1_BLOCKS * 4);     // 128*SB f32
  float* params = (float*)(w + 1536 + NMOM * K1_BLOCKS * 4 + 128 * SB * 4);  // 320 f32
  int* perm = (int*)(w + 1536 + NMOM * K1_BLOCKS * 4 + 128 * SB * 4 + 320 * 4);  // 48000 ints

  k_sort<<<1, 256, 0, stream>>>(npnts, perm);
  k_moments<<<K1_BLOCKS, 256, 0, stream>>>(vox, coords, npnts, P1);
  k_rowreduce<<<NMOM, 256, 0, stream>>>(P1, T1, K1_BLOCKS);
  k_fin1<<<1, 64, 0, stream>>>(T1, W1, g1, b1, params);
  k_stats2<<<SB, 256, 0, stream>>>(vox, coords, npnts, W1, W2, params, perm, P2);
  k_rowreduce<<<128, 256, 0, stream>>>(P2, T2, SB);
  k_fin2<<<1, 64, 0, stream>>>(T2, g2, b2, W2, T1, params);
  k_out<<<SB, 256, 0, stream>>>(vox, coords, npnts, W1, W2, params, perm, out);
}

// Round 7
// 323.500 us; speedup vs baseline: 3.3830x; 1.7536x over previous
//
#include <hip/hip_runtime.h>
#include <math.h>

#define NB 4
#define NPI 12000
#define NM 32
#define NPTS (NB*NPI*NM)      // 1536000
#define NPIL (NB*NPI)         // 48000

// k_moments config
#define K1_BLOCKS 1500
#define K1_STRIDE (K1_BLOCKS*256)   // 384000
#define K1_ITERS 4                  // NPTS / K1_STRIDE
#define NMOM 55                     // 9 Sf + 45 Sff + 1 valid-count

// heavy-kernel config: 128 points (4 sorted pillars) per batch
#define CHUNK 128
#define NBATCH (NPTS/CHUNK)   // 12000
#define SB 1024               // grid for k_stats2
#define LDH 68                // padded h1 row stride (floats)

// sort config
#define SLICE 188             // 256*188 = 48128 >= NPIL

// ---------------------------------------------------------------- helpers

__device__ __forceinline__ void make_f(float4 v, int4 cc, int np, int m, float zc, float f[9]) {
  const float cx = ((float)cc.w + 0.5f) * 0.16f + 0.0f;
  const float cy = ((float)cc.z + 0.5f) * 0.16f - 39.68f;
  f[0] = v.x; f[1] = v.y; f[2] = v.z; f[3] = v.w;
  f[4] = v.x - cx; f[5] = v.y - cy; f[6] = cx; f[7] = cy; f[8] = zc;
  const float msk = (m < np) ? 1.0f : 0.0f;
#pragma unroll
  for (int i = 0; i < 9; ++i) f[i] *= msk;
}

// ------------------------------------------------- K0: stable counting sort of
// pillars by np (33 bins). Single block, deterministic.

__global__ __launch_bounds__(256) void k_sort(
    const int* __restrict__ npnts, int* __restrict__ perm) {
  __shared__ int C[33][256];
  __shared__ int T[33], O[33];
  const int t = threadIdx.x;
#pragma unroll
  for (int b = 0; b < 33; ++b) C[b][t] = 0;
  __syncthreads();
  const int i0 = t * SLICE;
  const int i1 = (i0 + SLICE < NPIL) ? i0 + SLICE : NPIL;
  for (int i = i0; i < i1; ++i) C[npnts[i]][t]++;
  __syncthreads();
  if (t < 33) { int s = 0; for (int j = 0; j < 256; ++j) s += C[t][j]; T[t] = s; }
  __syncthreads();
  if (t == 0) { int r = 0; for (int b = 0; b < 33; ++b) { O[b] = r; r += T[b]; } }
  __syncthreads();
  if (t < 33) {
    int r = O[t];
    for (int j = 0; j < 256; ++j) { const int c = C[t][j]; C[t][j] = r; r += c; }
  }
  __syncthreads();
  for (int i = i0; i < i1; ++i) {
    const int b = npnts[i];
    const int p = C[b][t];
    C[b][t] = p + 1;
    perm[p] = i;
  }
}

// ------------------------------------------------- K1: f-moments + valid count

__global__ __launch_bounds__(256) void k_moments(
    const float4* __restrict__ vox, const int4* __restrict__ coords,
    const int* __restrict__ npnts, float* __restrict__ P1) {
  const int t = blockIdx.x * 256 + threadIdx.x;
  float acc[NMOM];
#pragma unroll
  for (int v = 0; v < NMOM; ++v) acc[v] = 0.0f;

#pragma unroll
  for (int j = 0; j < K1_ITERS; ++j) {
    const int pt = t + j * K1_STRIDE;
    const int pil = pt >> 5;
    const int m = pt & 31;
    const float4 v = vox[pt];
    const int4 cc = coords[pil];
    const int np = npnts[pil];
    float z = v.z;
#pragma unroll
    for (int s = 1; s < 32; s <<= 1) z += __shfl_xor(z, s, 32);
    const float zc = z * (1.0f / 32.0f);
    float f[9];
    make_f(v, cc, np, m, zc, f);
    int vi = 0;
#pragma unroll
    for (int i = 0; i < 9; ++i) acc[vi++] += f[i];
#pragma unroll
    for (int i = 0; i < 9; ++i)
#pragma unroll
      for (int jj = i; jj < 9; ++jj) acc[vi++] += f[i] * f[jj];
    acc[54] += (m < np) ? 1.0f : 0.0f;
  }

#pragma unroll
  for (int v = 0; v < NMOM; ++v) {
    float x = acc[v];
#pragma unroll
    for (int s = 1; s < 64; s <<= 1) x += __shfl_xor(x, s, 64);
    acc[v] = x;
  }
  __shared__ float red[4][NMOM];
  const int wave = threadIdx.x >> 6, lane = threadIdx.x & 63;
  if (lane == 0) {
#pragma unroll
    for (int v = 0; v < NMOM; ++v) red[wave][v] = acc[v];
  }
  __syncthreads();
  if (threadIdx.x < NMOM) {
    float s = red[0][threadIdx.x] + red[1][threadIdx.x] + red[2][threadIdx.x] + red[3][threadIdx.x];
    P1[threadIdx.x * K1_BLOCKS + blockIdx.x] = s;
  }
}

// ------------------------------------------------- generic row reduce (f32 -> f64)

__global__ __launch_bounds__(256) void k_rowreduce(
    const float* __restrict__ src, double* __restrict__ dst, int ncols) {
  const int row = blockIdx.x;
  const float* p = src + row * ncols;
  double sd = 0.0;
  for (int i = threadIdx.x; i < ncols; i += 256) sd += (double)p[i];
#pragma unroll
  for (int s = 1; s < 64; s <<= 1) sd += __shfl_xor(sd, s, 64);
  __shared__ double rd[4];
  const int wave = threadIdx.x >> 6, lane = threadIdx.x & 63;
  if (lane == 0) rd[wave] = sd;
  __syncthreads();
  if (threadIdx.x == 0) dst[row] = rd[0] + rd[1] + rd[2] + rd[3];
}

// ------------------------------------------------- finalize layer-1 BN params

__global__ void k_fin1(const double* __restrict__ T1, const float* __restrict__ W1,
                       const float* __restrict__ g1, const float* __restrict__ b1,
                       float* __restrict__ params) {
  const int c = threadIdx.x;  // 64
  double w[9];
#pragma unroll
  for (int i = 0; i < 9; ++i) w[i] = (double)W1[i * 64 + c];
  double mean = 0.0;
#pragma unroll
  for (int i = 0; i < 9; ++i) mean += w[i] * T1[i];
  mean /= (double)NPTS;
  double e2 = 0.0;
  int v = 9;
#pragma unroll
  for (int i = 0; i < 9; ++i)
#pragma unroll
    for (int j = i; j < 9; ++j) {
      const double t = T1[v++] * w[i] * w[j];
      e2 += (i == j) ? t : 2.0 * t;
    }
  e2 /= (double)NPTS;
  const double var = e2 - mean * mean;
  const double a = (double)g1[c] / sqrt(var + 0.001);
  params[c] = (float)a;
  params[64 + c] = (float)((double)b1[c] - mean * a);
}

// ------------------------------------------------- K3: layer-2 stats + y2 max/min
// Round-4 structure (barrier = register-pressure fence; round 5's barrier-free
// variant spilled). Sorted pillars -> chunk max(np) ~= mean(np). Phase B also
// tracks per-(pillar,channel) running max/min of y2 -> global, which lets the
// output pass skip all recompute (monotone-map identity, bit-exact).

__global__ __launch_bounds__(256, 4) void k_stats2(
    const float4* __restrict__ vox, const int4* __restrict__ coords,
    const int* __restrict__ npnts, const float* __restrict__ W1,
    const float* __restrict__ W2, const float* __restrict__ params,
    const int* __restrict__ perm, float* __restrict__ P2,
    float* __restrict__ Y2MAX, float* __restrict__ Y2MIN) {
  __shared__ __align__(16) float W1t[9 * 64];
  __shared__ __align__(16) float a1s[64], b1s[64];
  __shared__ __align__(16) float h1s[CHUNK * LDH];
  __shared__ float redS[4][64], redQ[4][64];

  const int t = threadIdx.x;
  for (int i = t; i < 576; i += 256) W1t[i] = W1[i];
  if (t < 64) { a1s[t] = params[t]; b1s[t] = params[64 + t]; }

  const int c = t & 63;
  float w2[64];
#pragma unroll
  for (int k = 0; k < 64; ++k) w2[k] = W2[k * 64 + c];
  __syncthreads();

  const int p_loc = t >> 1;
  const int ch_half = (t & 1) * 32;
  const int g = t >> 6;
  float psum = 0.0f, psq = 0.0f;

  for (int bb = blockIdx.x; bb < NBATCH; bb += SB) {
    // ---- phase A: h1 for 128 points (4 permuted pillars)
    const int pid = perm[bb * 4 + (p_loc >> 5)];
    const int m = p_loc & 31;
    const float4 v = vox[pid * 32 + m];
    const int4 cc = coords[pid];
    const int np = npnts[pid];
    float z = v.z;
#pragma unroll
    for (int s = 1; s < 64; s <<= 1) z += __shfl_xor(z, s, 64);
    const float zc = z * (1.0f / 64.0f);
    float f[9];
    make_f(v, cc, np, m, zc, f);
    float* row = &h1s[p_loc * LDH];
#pragma unroll
    for (int j = 0; j < 8; ++j) {
      const int c0 = ch_half + 4 * j;
      float y0 = 0, y1 = 0, y2 = 0, y3 = 0;
#pragma unroll
      for (int i = 0; i < 9; ++i) {
        const float4 w = *(const float4*)&W1t[i * 64 + c0];
        y0 = fmaf(f[i], w.x, y0);
        y1 = fmaf(f[i], w.y, y1);
        y2 = fmaf(f[i], w.z, y2);
        y3 = fmaf(f[i], w.w, y3);
      }
      const float4 a = *(const float4*)&a1s[c0];
      const float4 b = *(const float4*)&b1s[c0];
      float4 h;
      h.x = fmaxf(fmaf(y0, a.x, b.x), 0.0f);
      h.y = fmaxf(fmaf(y1, a.y, b.y), 0.0f);
      h.z = fmaxf(fmaf(y2, a.z, b.z), 0.0f);
      h.w = fmaxf(fmaf(y3, a.w, b.w), 0.0f);
      *(float4*)&row[c0] = h;
    }
    __syncthreads();
    // ---- phase B: valid points only; track running y2 max/min for this pillar
    const int pidB = perm[bb * 4 + g];
    const int np_g = npnts[pidB];
    float ymx = -INFINITY, ymn = INFINITY;
#pragma unroll 2
    for (int pp = 0; pp < np_g; ++pp) {
      const float4* hr = (const float4*)&h1s[(g * 32 + pp) * LDH];
      float y0 = 0, y1 = 0, y2 = 0, y3 = 0;
#pragma unroll
      for (int a4 = 0; a4 < 16; ++a4) {
        const float4 hv = hr[a4];   // broadcast read
        y0 = fmaf(hv.x, w2[4 * a4 + 0], y0);
        y1 = fmaf(hv.y, w2[4 * a4 + 1], y1);
        y2 = fmaf(hv.z, w2[4 * a4 + 2], y2);
        y3 = fmaf(hv.w, w2[4 * a4 + 3], y3);
      }
      const float y = (y0 + y1) + (y2 + y3);
      psum += y;
      psq = fmaf(y, y, psq);
      ymx = fmaxf(ymx, y);
      ymn = fminf(ymn, y);
    }
    Y2MAX[pidB * 64 + c] = ymx;   // coalesced (lane = channel)
    Y2MIN[pidB * 64 + c] = ymn;
    __syncthreads();
  }

  const int wave = t >> 6;
  redS[wave][c] = psum;
  redQ[wave][c] = psq;
  __syncthreads();
  if (t < 64) {
    const float s = redS[0][t] + redS[1][t] + redS[2][t] + redS[3][t];
    const float q = redQ[0][t] + redQ[1][t] + redQ[2][t] + redQ[3][t];
    P2[t * SB + blockIdx.x] = s;
    P2[(64 + t) * SB + blockIdx.x] = q;
  }
}

// ------------------------------------------------- finalize layer-2 BN params

__global__ void k_fin2(const double* __restrict__ T2, const float* __restrict__ g2,
                       const float* __restrict__ b2, const float* __restrict__ W2,
                       const double* __restrict__ T1, float* __restrict__ params) {
  const int c = threadIdx.x;  // 64
  const double nmask = (double)NPTS - T1[54];
  double y20 = 0.0;
  for (int k = 0; k < 64; ++k) {
    const float h0 = fmaxf(params[64 + k], 0.0f);   // h1_0[k] = relu(b1adj[k])
    y20 += (double)h0 * (double)W2[k * 64 + c];
  }
  const double sum = T2[c] + nmask * y20;
  const double sq  = T2[64 + c] + nmask * y20 * y20;
  const double mean = sum / (double)NPTS;
  const double var = sq / (double)NPTS - mean * mean;
  const double a = (double)g2[c] / sqrt(var + 0.001);
  const double badj = (double)b2[c] - mean * a;
  params[128 + c] = (float)a;
  params[192 + c] = (float)badj;
  params[256 + c] = (float)fmax(a * y20 + badj, 0.0);   // h2_0[c] (relu)
}

// ------------------------------------------------- K5: final output pass.
// h2 = relu(a2*y2 + b2adj) is monotone in y2 (direction = sign(a2)); fma/relu
// rounding is monotone, so max over points = the map applied to max(y2)
// (or min(y2) if a2<0) BIT-EXACTLY. Pure streaming pass, ~37 MB.

__global__ __launch_bounds__(256) void k_final(
    const int* __restrict__ npnts, const float* __restrict__ params,
    const float* __restrict__ Y2MAX, const float* __restrict__ Y2MIN,
    float* __restrict__ out) {
  const int idx = blockIdx.x * 256 + threadIdx.x;   // NPIL*64 total
  const int pid = idx >> 6;
  const int c = idx & 63;
  const int np = npnts[pid];
  const float a2 = params[128 + c];
  const float b2 = params[192 + c];
  const float h20 = params[256 + c];
  const float mx = Y2MAX[idx];
  const float mn = Y2MIN[idx];
  const float sel = (a2 >= 0.0f) ? mx : mn;
  float h = (np > 0) ? fmaxf(fmaf(sel, a2, b2), 0.0f) : 0.0f;
  if (np < 32) h = fmaxf(h, h20);
  out[idx] = h;
}

// ---------------------------------------------------------------- launch

extern "C" void kernel_launch(void* const* d_in, const int* in_sizes, int n_in,
                              void* d_out, int out_size, void* d_ws, size_t ws_size,
                              hipStream_t stream) {
  const float4* vox = (const float4*)d_in[0];
  const int4* coords = (const int4*)d_in[1];
  const int* npnts = (const int*)d_in[2];
  const float* W1 = (const float*)d_in[3];
  const float* g1 = (const float*)d_in[4];
  const float* b1 = (const float*)d_in[5];
  const float* W2 = (const float*)d_in[6];
  const float* g2 = (const float*)d_in[7];
  const float* b2 = (const float*)d_in[8];
  float* out = (float*)d_out;

  char* w = (char*)d_ws;
  size_t off = 0;
  double* T1 = (double*)(w + off); off += 512;                 // 55 doubles
  double* T2 = (double*)(w + off); off += 1024;                // 128 doubles
  float* P1 = (float*)(w + off); off += NMOM * K1_BLOCKS * 4;  // 330 KB
  float* P2 = (float*)(w + off); off += 128 * SB * 4;          // 524 KB
  float* params = (float*)(w + off); off += 512 * 4;           // 320 used
  int* perm = (int*)(w + off); off += NPIL * 4;                // 192 KB
  float* Y2MAX = (float*)(w + off); off += (size_t)NPIL * 64 * 4;  // 12.3 MB
  float* Y2MIN = (float*)(w + off); off += (size_t)NPIL * 64 * 4;  // 12.3 MB

  k_sort<<<1, 256, 0, stream>>>(npnts, perm);
  k_moments<<<K1_BLOCKS, 256, 0, stream>>>(vox, coords, npnts, P1);
  k_rowreduce<<<NMOM, 256, 0, stream>>>(P1, T1, K1_BLOCKS);
  k_fin1<<<1, 64, 0, stream>>>(T1, W1, g1, b1, params);
  k_stats2<<<SB, 256, 0, stream>>>(vox, coords, npnts, W1, W2, params, perm, P2, Y2MAX, Y2MIN);
  k_rowreduce<<<128, 256, 0, stream>>>(P2, T2, SB);
  k_fin2<<<1, 64, 0, stream>>>(T2, g2, b2, W2, T1, params);
  k_final<<<(NPIL * 64) / 256, 256, 0, stream>>>(npnts, params, Y2MAX, Y2MIN, out);
}